// Round 1
// baseline (1708.403 us; speedup 1.0000x reference)
//
#include <hip/hip_runtime.h>
#include <hip/hip_cooperative_groups.h>
#include <stdint.h>

namespace cg = cooperative_groups;

#define LVL 24
#define NN  8192
#define DIN 256
#define DD  128
#define BM  32
#define NTILES 512   // (NN/BM) node-tiles x 2 d-halves

typedef __attribute__((ext_vector_type(8))) short bf16x8;
typedef __attribute__((ext_vector_type(4))) float f32x4;

__device__ __forceinline__ float b2f(unsigned short u) {
    union { unsigned int i; float f; } v; v.i = ((unsigned int)u) << 16; return v.f;
}
__device__ __forceinline__ unsigned short f2b(float f) {
    union { float f; unsigned int i; } v; v.f = f;
    unsigned int x = v.i;
    return (unsigned short)((x + 0x7fffu + ((x >> 16) & 1u)) >> 16);  // RNE
}
__device__ __forceinline__ float sig_(float x) { return 1.0f / (1.0f + __expf(-x)); }

__device__ __forceinline__ float ldf(const void* p, size_t i, int isf) {
    return isf ? ((const float*)p)[i] : b2f(((const unsigned short*)p)[i]);
}

// ---------------- dtype detector (unchanged) ----------------
__global__ void detect_kernel(const unsigned short* __restrict__ t, int* __restrict__ flag) {
    __shared__ int cnt;
    if (threadIdx.x == 0) cnt = 0;
    __syncthreads();
    int bad = 0;
    #pragma unroll
    for (int r = 0; r < 4; ++r) {
        unsigned short u = t[(threadIdx.x * 4 + r) * 2];
        int e = (u >> 7) & 255;
        bad += (e >= 136 || (e >= 1 && e <= 90)) ? 1 : 0;
    }
    atomicAdd(&cnt, bad);
    __syncthreads();
    if (threadIdx.x == 0) *flag = (cnt > 16) ? 1 : 0;
}

// ---------------- weight conversion into FRAGMENT-MAJOR packed layout ----------------
// Logical weight rows: [0,512)=W_w(f,i,u,o); [512,640)=U_f1; [640,768)=U_f2; [768,1152)=U_iuo.
// Packed element index: ((g*8+dt)*8 + kk)*512 + (q*16+m)*8 + j
//   where row = g*128 + dt*16 + m, col = kk*32 + q*8 + j.
// A wave's B-fragment load (g,dt,kk) is then 64 lanes x 16B fully contiguous (1 KB).
__global__ __launch_bounds__(256)
void convert_kernel(const void* Ww, const void* Wb, const void* Uf1, const void* Uf2,
                    const void* Uiuo, const void* hini, const void* cini,
                    unsigned short* __restrict__ wpack, float* __restrict__ bias,
                    unsigned short* __restrict__ hinit_b, float* __restrict__ cinit_f,
                    const int* __restrict__ flag) {
    const int isf = *flag;
    const int bid = blockIdx.x;
    const int t = threadIdx.x;
    if (bid < 1152) {
        const int row = bid, col = t;
        float v;
        if (row < 512)       v = ldf(Ww,   (size_t)row * DIN + col, isf);
        else if (row < 640)  v = ldf(Uf1,  (size_t)(row - 512) * DIN + col, isf);
        else if (row < 768)  v = ldf(Uf2,  (size_t)(row - 640) * DIN + col, isf);
        else                 v = ldf(Uiuo, (size_t)(row - 768) * DIN + col, isf);
        const int g  = row >> 7;
        const int wr = row & 127;
        const int dt = wr >> 4;
        const int mm = wr & 15;
        const int kk = col >> 5;
        const int q  = (col >> 3) & 3;
        const int j  = col & 7;
        const size_t pos = (size_t)((g * 8 + dt) * 8 + kk) * 512 + (q * 16 + mm) * 8 + j;
        wpack[pos] = f2b(v);
    } else if (bid == 1152) {
        bias[t] = ldf(Wb, t, isf);
    } else if (bid == 1153) {
        bias[256 + t] = ldf(Wb, 256 + t, isf);
    } else {
        if (t < 128) hinit_b[t] = f2b(ldf(hini, t, isf));
        else if (t < 256) cinit_f[t - 128] = ldf(cini, t - 128, isf);
    }
}

// ---------------- fused all-levels cooperative kernel ----------------
// Grid-strided over 512 tiles (tile = node-tile*2 + d-half); grid.sync() between levels.
// LDS: fragment-linear x/h stores -> conflict-free ds_read_b128 in the MFMA loop.
__global__ __launch_bounds__(256, 2)
void fused_kernel(const void* __restrict__ xbase,
                  const int* __restrict__ idxall,      // [L, NN, 2]
                  unsigned short* __restrict__ hb0,    // [NN, DD] bf16 ping
                  unsigned short* __restrict__ hb1,    // [NN, DD] bf16 pong
                  float* __restrict__ out,             // [2L, NN, DD] (h slab | c slab)
                  const unsigned short* __restrict__ wpack,
                  const float* __restrict__ bias,
                  const unsigned short* __restrict__ hinit_b,
                  const float* __restrict__ cinit_f,
                  const int* __restrict__ flag) {
    // [kk][q][m2][8] bf16, m2 in [0,32): element index = kk*1024 + q*256 + m2*8
    __shared__ unsigned short xs[8 * 4 * 32 * 8];   // 16 KB
    __shared__ unsigned short hs[8 * 4 * 32 * 8];   // 16 KB

    const int tid  = threadIdx.x;
    const int isf  = *flag;
    const int lane = tid & 63;
    const int wave = tid >> 6;
    const int m    = lane & 15;
    const int q    = lane >> 4;

    cg::grid_group grid = cg::this_grid();

    for (int l = 0; l < LVL; ++l) {
        const int first = (l == 0) ? 1 : 0;
        const int* __restrict__ idx = idxall + (size_t)l * NN * 2;
        const unsigned short* __restrict__ hprev = (l & 1) ? hb0 : hb1;
        unsigned short* __restrict__ hnew        = (l & 1) ? hb1 : hb0;
        const float* __restrict__ cprev = out + (size_t)(LVL + l - 1) * NN * DD; // guarded by first at l=0
        float* __restrict__ outh = out + (size_t)l * NN * DD;
        float* __restrict__ outc = out + (size_t)(LVL + l) * NN * DD;

        for (int rr = blockIdx.x; rr < NTILES; rr += gridDim.x) {
            // XCD-aware map: the two d-halves of a node-tile land on the same XCD (L2 x-reuse)
            const int tile = ((rr & 7) << 6) | (rr >> 3);
            const int bm = tile >> 1;
            const int yh = tile & 1;

            // ---- stage x tile: thread (r = tid>>3, kk = tid&7), 32 cols each ----
            {
                const int r  = tid >> 3;
                const int kk = tid & 7;
                const size_t re = (size_t)l * NN * DIN + (size_t)(bm * BM + r) * DIN + kk * 32;
                unsigned short tmp[32];
                if (isf) {
                    const float4* xr = (const float4*)((const float*)xbase + re);
                    #pragma unroll
                    for (int p = 0; p < 8; ++p) {
                        float4 v = xr[p];
                        tmp[p * 4 + 0] = f2b(v.x); tmp[p * 4 + 1] = f2b(v.y);
                        tmp[p * 4 + 2] = f2b(v.z); tmp[p * 4 + 3] = f2b(v.w);
                    }
                } else {
                    const uint4* xr = (const uint4*)((const unsigned short*)xbase + re);
                    #pragma unroll
                    for (int p = 0; p < 4; ++p) *(uint4*)&tmp[p * 8] = xr[p];
                }
                #pragma unroll
                for (int qq = 0; qq < 4; ++qq)
                    *(uint4*)&xs[kk * 1024 + qq * 256 + r * 8] = *(const uint4*)&tmp[qq * 8];
            }
            // ---- gather children h: 4 threads per (row, child), 64B each ----
            {
                const int slot = tid >> 2;
                const int r = slot >> 1;
                const int s = slot & 1;
                const int part = tid & 3;
                const int node = bm * BM + r;
                const int ai = idx[node * 2 + s];
                const unsigned short* src = (first || ai < 0)
                    ? (hinit_b + part * 32)
                    : (hprev + (size_t)ai * DD + part * 32);
                const uint4* s4 = (const uint4*)src;
                uint4 v0 = s4[0], v1 = s4[1], v2 = s4[2], v3 = s4[3];
                const int kk = s * 4 + part;   // concat col base = kk*32
                *(uint4*)&hs[kk * 1024 + 0 * 256 + r * 8] = v0;
                *(uint4*)&hs[kk * 1024 + 1 * 256 + r * 8] = v1;
                *(uint4*)&hs[kk * 1024 + 2 * 256 + r * 8] = v2;
                *(uint4*)&hs[kk * 1024 + 3 * 256 + r * 8] = v3;
            }
            __syncthreads();

            const int d0 = yh * 64 + wave * 16;
            const int dt = d0 >> 4;
            const int d  = d0 + m;

            const unsigned short* wp[9];
            #pragma unroll
            for (int g = 0; g < 9; ++g)
                wp[g] = wpack + (size_t)(g * 8 + dt) * 4096 + (size_t)lane * 8;

            f32x4 acc[9][2];
            #pragma unroll
            for (int g = 0; g < 9; ++g) { acc[g][0] = (f32x4)0.0f; acc[g][1] = (f32x4)0.0f; }

            #pragma unroll
            for (int kk = 0; kk < 8; ++kk) {
                const int xo = kk * 1024 + q * 256 + m * 8;
                bf16x8 a0 = *(const bf16x8*)&xs[xo];
                bf16x8 a1 = *(const bf16x8*)&xs[xo + 128];
                bf16x8 g0 = *(const bf16x8*)&hs[xo];
                bf16x8 g1 = *(const bf16x8*)&hs[xo + 128];
                #pragma unroll
                for (int g = 0; g < 4; ++g) {
                    bf16x8 b = *(const bf16x8*)(wp[g] + kk * 512);
                    acc[g][0] = __builtin_amdgcn_mfma_f32_16x16x32_bf16(a0, b, acc[g][0], 0, 0, 0);
                    acc[g][1] = __builtin_amdgcn_mfma_f32_16x16x32_bf16(a1, b, acc[g][1], 0, 0, 0);
                }
                #pragma unroll
                for (int g = 4; g < 9; ++g) {
                    bf16x8 b = *(const bf16x8*)(wp[g] + kk * 512);
                    acc[g][0] = __builtin_amdgcn_mfma_f32_16x16x32_bf16(g0, b, acc[g][0], 0, 0, 0);
                    acc[g][1] = __builtin_amdgcn_mfma_f32_16x16x32_bf16(g1, b, acc[g][1], 0, 0, 0);
                }
            }

            // ---- pointwise LSTM (C layout: col=lane&15 -> d, row=q*4+j -> node) ----
            const float bfv = bias[d], biv = bias[128 + d], buv = bias[256 + d], bov = bias[384 + d];
            const float ci = cinit_f[d];
            #pragma unroll
            for (int mt = 0; mt < 2; ++mt) {
                const int rowb = bm * BM + mt * 16 + q * 4;
                #pragma unroll
                for (int j = 0; j < 4; ++j) {
                    const int nd = rowb + j;
                    const int a  = idx[nd * 2 + 0];
                    const int b_ = idx[nd * 2 + 1];
                    const float ca = (first || a  < 0) ? ci : cprev[(size_t)a  * DD + d];
                    const float cb = (first || b_ < 0) ? ci : cprev[(size_t)b_ * DD + d];
                    const float fx = acc[0][mt][j] + bfv;
                    const float ix = acc[1][mt][j] + biv;
                    const float ux = acc[2][mt][j] + buv;
                    const float ox = acc[3][mt][j] + bov;
                    const float f1 = sig_(fx + acc[4][mt][j]);
                    const float f2 = sig_(fx + acc[5][mt][j]);
                    const float ig = sig_(ix + acc[6][mt][j]);
                    const float ug = tanhf(ux + acc[7][mt][j]);
                    const float og = sig_(ox + acc[8][mt][j]);
                    const float nc = ig * ug + f1 * ca + f2 * cb;
                    const float nh = og * tanhf(nc);
                    const size_t o = (size_t)nd * DD + d;
                    hnew[o] = f2b(nh);
                    outh[o] = nh;
                    outc[o] = nc;      // doubles as next level's c-state
                }
            }
            __syncthreads();   // LDS reuse guard (multi-tile fallback path)
        }
        grid.sync();           // level barrier: h/c of level l visible to all XCDs
    }
}

extern "C" void kernel_launch(void* const* d_in, const int* in_sizes, int n_in,
                              void* d_out, int out_size, void* d_ws, size_t ws_size,
                              hipStream_t stream) {
    const void* tensor  = d_in[0];
    const int*  indices = (const int*)d_in[1];
    const void* h_init  = d_in[2];
    const void* c_init  = d_in[3];
    const void* Ww      = d_in[4];
    const void* Wb      = d_in[5];
    const void* Uf1     = d_in[6];
    const void* Uf2     = d_in[7];
    const void* Uiuo    = d_in[8];
    float* out = (float*)d_out;   // fp32: [h(L,N,D) | c(L,N,D)]

    char* wsb = (char*)d_ws;
    int* flag                = (int*)wsb;                               // @0
    unsigned short* wpack    = (unsigned short*)(wsb + 256);            // 589,824 B
    float* bias              = (float*)(wsb + 590336);                  // 2 KB
    unsigned short* hinit_b  = (unsigned short*)(wsb + 592640);         // 256 B
    float* cinit_f           = (float*)(wsb + 593152);                  // 512 B
    unsigned short* hb0      = (unsigned short*)(wsb + (1u << 20));             // 2 MB
    unsigned short* hb1      = (unsigned short*)(wsb + (1u << 20) + 2097152);   // 2 MB

    detect_kernel<<<1, 64, 0, stream>>>((const unsigned short*)tensor, flag);
    convert_kernel<<<1155, 256, 0, stream>>>(Ww, Wb, Uf1, Uf2, Uiuo, h_init, c_init,
                                             wpack, bias, hinit_b, cinit_f, flag);

    static int nb = 0;
    if (nb == 0) {
        if (hipOccupancyMaxActiveBlocksPerMultiprocessor(&nb, fused_kernel, 256, 0) != hipSuccess
            || nb <= 0)
            nb = 1;
    }
    int grid = NTILES;
    if (nb * 256 < grid) grid = nb * 256;

    void* kargs[] = { (void*)&tensor, (void*)&indices, (void*)&hb0, (void*)&hb1,
                      (void*)&out, (void*)&wpack, (void*)&bias, (void*)&hinit_b,
                      (void*)&cinit_f, (void*)&flag };
    hipLaunchCooperativeKernel((const void*)fused_kernel, dim3(grid), dim3(256),
                               kargs, 0, stream);
}

// Round 2
// 769.892 us; speedup vs baseline: 2.2190x; 2.2190x over previous
//
#include <hip/hip_runtime.h>
#include <stdint.h>

#define LVL 24
#define NN  8192
#define DIN 256
#define DD  128
#define BM  16   // nodes per block; block covers ALL 128 d (8 waves, one 16-d tile each)

typedef __attribute__((ext_vector_type(8))) short bf16x8;
typedef __attribute__((ext_vector_type(4))) float f32x4;

__device__ __forceinline__ float b2f(unsigned short u) {
    union { unsigned int i; float f; } v; v.i = ((unsigned int)u) << 16; return v.f;
}
__device__ __forceinline__ unsigned short f2b(float f) {
    union { float f; unsigned int i; } v; v.f = f;
    unsigned int x = v.i;
    return (unsigned short)((x + 0x7fffu + ((x >> 16) & 1u)) >> 16);  // RNE
}
__device__ __forceinline__ float sig_(float x) { return 1.0f / (1.0f + __expf(-x)); }

__device__ __forceinline__ float ldf(const void* p, size_t i, int isf) {
    return isf ? ((const float*)p)[i] : b2f(((const unsigned short*)p)[i]);
}

// ---------------- dtype detector (unchanged) ----------------
__global__ void detect_kernel(const unsigned short* __restrict__ t, int* __restrict__ flag) {
    __shared__ int cnt;
    if (threadIdx.x == 0) cnt = 0;
    __syncthreads();
    int bad = 0;
    #pragma unroll
    for (int r = 0; r < 4; ++r) {
        unsigned short u = t[(threadIdx.x * 4 + r) * 2];
        int e = (u >> 7) & 255;
        bad += (e >= 136 || (e >= 1 && e <= 90)) ? 1 : 0;
    }
    atomicAdd(&cnt, bad);
    __syncthreads();
    if (threadIdx.x == 0) *flag = (cnt > 16) ? 1 : 0;
}

// ---------------- weight conversion into FRAGMENT-MAJOR packed layout ----------------
// Logical rows: [0,512)=W_w(f,i,u,o); [512,640)=U_f1; [640,768)=U_f2; [768,1152)=U_iuo.
// Packed element index: ((g*8+dt)*8 + kk)*512 + (q*16+m)*8 + j
//   where row = g*128 + dt*16 + m, col = kk*32 + q*8 + j.
// A wave's B-fragment load (g,dt,kk) is 64 lanes x 16B fully contiguous (1 KB).
__global__ __launch_bounds__(256)
void convert_kernel(const void* Ww, const void* Wb, const void* Uf1, const void* Uf2,
                    const void* Uiuo, const void* hini, const void* cini,
                    unsigned short* __restrict__ wpack, float* __restrict__ bias,
                    unsigned short* __restrict__ hinit_b, float* __restrict__ cinit_f,
                    const int* __restrict__ flag) {
    const int isf = *flag;
    const int bid = blockIdx.x;
    const int t = threadIdx.x;
    if (bid < 1152) {
        const int row = bid, col = t;
        float v;
        if (row < 512)       v = ldf(Ww,   (size_t)row * DIN + col, isf);
        else if (row < 640)  v = ldf(Uf1,  (size_t)(row - 512) * DIN + col, isf);
        else if (row < 768)  v = ldf(Uf2,  (size_t)(row - 640) * DIN + col, isf);
        else                 v = ldf(Uiuo, (size_t)(row - 768) * DIN + col, isf);
        const int g  = row >> 7;
        const int wr = row & 127;
        const int dt = wr >> 4;
        const int mm = wr & 15;
        const int kk = col >> 5;
        const int q  = (col >> 3) & 3;
        const int j  = col & 7;
        const size_t pos = (size_t)((g * 8 + dt) * 8 + kk) * 512 + (q * 16 + mm) * 8 + j;
        wpack[pos] = f2b(v);
    } else if (bid == 1152) {
        bias[t] = ldf(Wb, t, isf);
    } else if (bid == 1153) {
        bias[256 + t] = ldf(Wb, 256 + t, isf);
    } else {
        if (t < 128) hinit_b[t] = f2b(ldf(hini, t, isf));
        else if (t < 256) cinit_f[t - 128] = ldf(cini, t - 128, isf);
    }
}

// ---------------- one tree level: BM=16 nodes x all 128 d, 512 threads ----------------
// LDS fragment layout for x/h: element (kk, q, r, j) at index kk*512 + q*128 + r*8 + j
//   (ushorts) == row r, col kk*32 + q*8 + j of the [16 x 256] tile.
// MFMA read (lane m,q): 16B at kk*1024 + q*256 + m*16 bytes -> 16-lane contiguous, conflict-free.
// Stores are 16-lane contiguous 256B segments -> conflict-free.
__global__ __launch_bounds__(512, 4)
void level_kernel(const void* __restrict__ xbase, int level,
                  const int* __restrict__ idx,            // [NN,2] this level
                  const unsigned short* __restrict__ hprev, // [NN,DD] bf16
                  const float* __restrict__ cprev,        // [NN,DD] fp32 (out slab l-1)
                  unsigned short* __restrict__ hnew,      // [NN,DD] bf16
                  float* __restrict__ outh,               // [NN,DD] fp32
                  float* __restrict__ outc,               // [NN,DD] fp32 (c state for l+1)
                  const unsigned short* __restrict__ wpack,
                  const float* __restrict__ bias,
                  const unsigned short* __restrict__ hinit_b,
                  const float* __restrict__ cinit_f,
                  const int* __restrict__ flag,
                  int first) {
    __shared__ unsigned short xs[4096];      // 8 KB
    __shared__ unsigned short hs[4096];      // 8 KB
    __shared__ float cs[32 * 132];           // 16.5 KB, padded rows (132 floats)

    const int tid = threadIdx.x;
    const int isf = *flag;
    const int bm  = blockIdx.x;

    // ---- stage x tile: thread (u = tid>>4 col-octet, r = tid&15 row) ----
    {
        const int u = tid >> 4;          // 0..31
        const int r = tid & 15;
        const int kk = u >> 2, q = u & 3;
        const size_t re = (size_t)level * NN * DIN + (size_t)(bm * BM + r) * DIN + u * 8;
        union { unsigned short us[8]; uint4 v; } t;
        if (isf) {
            const float4* xr = (const float4*)((const float*)xbase + re);
            float4 v0 = xr[0], v1 = xr[1];
            t.us[0] = f2b(v0.x); t.us[1] = f2b(v0.y); t.us[2] = f2b(v0.z); t.us[3] = f2b(v0.w);
            t.us[4] = f2b(v1.x); t.us[5] = f2b(v1.y); t.us[6] = f2b(v1.z); t.us[7] = f2b(v1.w);
        } else {
            t.v = *(const uint4*)((const unsigned short*)xbase + re);
        }
        *(uint4*)&xs[kk * 512 + q * 128 + r * 8] = t.v;
    }

    // ---- gather children h (16B/thread) and c (32B/thread) with init-select ----
    {
        const int r    = tid & 15;
        const int s    = (tid >> 4) & 1;
        const int part = tid >> 5;       // 0..15 (octet of the 128-wide child row)
        const int ai = idx[(bm * BM + r) * 2 + s];
        const int use_init = (first || ai < 0);

        const unsigned short* hsrc = use_init ? (hinit_b + part * 8)
                                              : (hprev + (size_t)ai * DD + part * 8);
        uint4 hv = *(const uint4*)hsrc;
        const int col = s * 128 + part * 8;          // concat col in [0,256)
        const int kk = col >> 5, q = (col >> 3) & 3;
        *(uint4*)&hs[kk * 512 + q * 128 + r * 8] = hv;

        const float* csrc = use_init ? (cinit_f + part * 8)
                                     : (cprev + (size_t)ai * DD + part * 8);
        float4 c0 = ((const float4*)csrc)[0];
        float4 c1 = ((const float4*)csrc)[1];
        float* cdst = &cs[(s * 16 + r) * 132 + part * 8];
        ((float4*)cdst)[0] = c0;
        ((float4*)cdst)[1] = c1;
    }
    __syncthreads();

    // ---- MFMA: wave dt handles d-range [dt*16, dt*16+16), 9 gates, K=256 in 8 steps ----
    const int lane = tid & 63;
    const int dt   = tid >> 6;           // 0..7
    const int m    = lane & 15;
    const int q    = lane >> 4;
    const int d    = dt * 16 + m;

    const unsigned short* wb = wpack + (size_t)dt * 4096 + (size_t)lane * 8;
    // fragment (g, kk) at wb + g*32768 + kk*512 (ushort units)

    f32x4 acc[9];
    #pragma unroll
    for (int g = 0; g < 9; ++g) acc[g] = (f32x4)0.0f;

    #pragma unroll
    for (int kk = 0; kk < 8; ++kk) {
        const int xo = kk * 512 + q * 128 + m * 8;
        bf16x8 a = *(const bf16x8*)&xs[xo];
        bf16x8 h = *(const bf16x8*)&hs[xo];
        #pragma unroll
        for (int g = 0; g < 4; ++g) {
            bf16x8 b = *(const bf16x8*)(wb + (size_t)g * 32768 + kk * 512);
            acc[g] = __builtin_amdgcn_mfma_f32_16x16x32_bf16(a, b, acc[g], 0, 0, 0);
        }
        #pragma unroll
        for (int g = 4; g < 9; ++g) {
            bf16x8 b = *(const bf16x8*)(wb + (size_t)g * 32768 + kk * 512);
            acc[g] = __builtin_amdgcn_mfma_f32_16x16x32_bf16(h, b, acc[g], 0, 0, 0);
        }
    }

    // ---- pointwise LSTM: acc[g][j] -> node row q*4+j, dim d; c from LDS ----
    const float bfv = bias[d], biv = bias[128 + d], buv = bias[256 + d], bov = bias[384 + d];
    #pragma unroll
    for (int j = 0; j < 4; ++j) {
        const int rr = q * 4 + j;
        const int nd = bm * BM + rr;
        const float ca = cs[rr * 132 + d];
        const float cb = cs[(16 + rr) * 132 + d];
        const float fx = acc[0][j] + bfv;
        const float ix = acc[1][j] + biv;
        const float ux = acc[2][j] + buv;
        const float ox = acc[3][j] + bov;
        const float f1 = sig_(fx + acc[4][j]);
        const float f2 = sig_(fx + acc[5][j]);
        const float ig = sig_(ix + acc[6][j]);
        const float ug = tanhf(ux + acc[7][j]);
        const float og = sig_(ox + acc[8][j]);
        const float nc = ig * ug + f1 * ca + f2 * cb;
        const float nh = og * tanhf(nc);
        const size_t o = (size_t)nd * DD + d;
        hnew[o] = f2b(nh);
        outh[o] = nh;
        outc[o] = nc;
    }
}

extern "C" void kernel_launch(void* const* d_in, const int* in_sizes, int n_in,
                              void* d_out, int out_size, void* d_ws, size_t ws_size,
                              hipStream_t stream) {
    const void* tensor  = d_in[0];
    const int*  indices = (const int*)d_in[1];
    const void* h_init  = d_in[2];
    const void* c_init  = d_in[3];
    const void* Ww      = d_in[4];
    const void* Wb      = d_in[5];
    const void* Uf1     = d_in[6];
    const void* Uf2     = d_in[7];
    const void* Uiuo    = d_in[8];
    float* out = (float*)d_out;   // fp32: [h(L,N,D) | c(L,N,D)]

    char* wsb = (char*)d_ws;
    int* flag                = (int*)wsb;                               // @0
    unsigned short* wpack    = (unsigned short*)(wsb + 256);            // 589,824 B
    float* bias              = (float*)(wsb + 590336);                  // 2 KB
    unsigned short* hinit_b  = (unsigned short*)(wsb + 592640);         // 256 B
    float* cinit_f           = (float*)(wsb + 593152);                  // 512 B
    unsigned short* hb0      = (unsigned short*)(wsb + (1u << 20));             // 2 MB
    unsigned short* hb1      = (unsigned short*)(wsb + (1u << 20) + 2097152);   // 2 MB

    detect_kernel<<<1, 64, 0, stream>>>((const unsigned short*)tensor, flag);
    convert_kernel<<<1155, 256, 0, stream>>>(Ww, Wb, Uf1, Uf2, Uiuo, h_init, c_init,
                                             wpack, bias, hinit_b, cinit_f, flag);

    unsigned short* hp = hb0;
    unsigned short* hn = hb1;
    for (int l = 0; l < LVL; ++l) {
        const float* cprev = (l == 0) ? (const float*)out
                                      : (const float*)(out + (size_t)(LVL + l - 1) * NN * DD);
        level_kernel<<<NN / BM, 512, 0, stream>>>(
            tensor, l,
            indices + (size_t)l * NN * 2,
            hp, cprev, hn,
            out + (size_t)l * NN * DD,
            out + (size_t)(LVL + l) * NN * DD,
            wpack, bias, hinit_b, cinit_f, flag, (l == 0) ? 1 : 0);
        unsigned short* th = hp; hp = hn; hn = th;
    }
}

// Round 3
// 747.924 us; speedup vs baseline: 2.2842x; 1.0294x over previous
//
#include <hip/hip_runtime.h>
#include <stdint.h>

#define LVL 24
#define NN  8192
#define DIN 256
#define DD  128
#define BM  32   // nodes per block; block covers a 64-wide d-half (4 waves, 2 m-tiles each)

typedef __attribute__((ext_vector_type(8))) short bf16x8;
typedef __attribute__((ext_vector_type(4))) float f32x4;

__device__ __forceinline__ float b2f(unsigned short u) {
    union { unsigned int i; float f; } v; v.i = ((unsigned int)u) << 16; return v.f;
}
__device__ __forceinline__ unsigned short f2b(float f) {
    union { float f; unsigned int i; } v; v.f = f;
    unsigned int x = v.i;
    return (unsigned short)((x + 0x7fffu + ((x >> 16) & 1u)) >> 16);  // RNE
}
__device__ __forceinline__ float sig_(float x) { return 1.0f / (1.0f + __expf(-x)); }

__device__ __forceinline__ float ldf(const void* p, size_t i, int isf) {
    return isf ? ((const float*)p)[i] : b2f(((const unsigned short*)p)[i]);
}

// ---------------- dtype detector (unchanged) ----------------
__global__ void detect_kernel(const unsigned short* __restrict__ t, int* __restrict__ flag) {
    __shared__ int cnt;
    if (threadIdx.x == 0) cnt = 0;
    __syncthreads();
    int bad = 0;
    #pragma unroll
    for (int r = 0; r < 4; ++r) {
        unsigned short u = t[(threadIdx.x * 4 + r) * 2];
        int e = (u >> 7) & 255;
        bad += (e >= 136 || (e >= 1 && e <= 90)) ? 1 : 0;
    }
    atomicAdd(&cnt, bad);
    __syncthreads();
    if (threadIdx.x == 0) *flag = (cnt > 16) ? 1 : 0;
}

// ---------------- weight conversion into FRAGMENT-MAJOR packed layout (unchanged) ----------------
// Logical rows: [0,512)=W_w(f,i,u,o); [512,640)=U_f1; [640,768)=U_f2; [768,1152)=U_iuo.
// Packed element index: ((g*8+dt)*8 + kk)*512 + (q*16+m)*8 + j
//   where row = g*128 + dt*16 + m, col = kk*32 + q*8 + j.
// A wave's B-fragment load (g,dt,kk) is 64 lanes x 16B fully contiguous (1 KB).
__global__ __launch_bounds__(256)
void convert_kernel(const void* Ww, const void* Wb, const void* Uf1, const void* Uf2,
                    const void* Uiuo, const void* hini, const void* cini,
                    unsigned short* __restrict__ wpack, float* __restrict__ bias,
                    unsigned short* __restrict__ hinit_b, float* __restrict__ cinit_f,
                    const int* __restrict__ flag) {
    const int isf = *flag;
    const int bid = blockIdx.x;
    const int t = threadIdx.x;
    if (bid < 1152) {
        const int row = bid, col = t;
        float v;
        if (row < 512)       v = ldf(Ww,   (size_t)row * DIN + col, isf);
        else if (row < 640)  v = ldf(Uf1,  (size_t)(row - 512) * DIN + col, isf);
        else if (row < 768)  v = ldf(Uf2,  (size_t)(row - 640) * DIN + col, isf);
        else                 v = ldf(Uiuo, (size_t)(row - 768) * DIN + col, isf);
        const int g  = row >> 7;
        const int wr = row & 127;
        const int dt = wr >> 4;
        const int mm = wr & 15;
        const int kk = col >> 5;
        const int q  = (col >> 3) & 3;
        const int j  = col & 7;
        const size_t pos = (size_t)((g * 8 + dt) * 8 + kk) * 512 + (q * 16 + mm) * 8 + j;
        wpack[pos] = f2b(v);
    } else if (bid == 1152) {
        bias[t] = ldf(Wb, t, isf);
    } else if (bid == 1153) {
        bias[256 + t] = ldf(Wb, 256 + t, isf);
    } else {
        if (t < 128) hinit_b[t] = f2b(ldf(hini, t, isf));
        else if (t < 256) cinit_f[t - 128] = ldf(cini, t - 128, isf);
    }
}

// ---------------- one tree level: BM=32 nodes x 64-d half, 256 threads ----------------
// x/h LDS fragment layout: element (kk, q, r, j) at ushort index kk*1024 + q*256 + r*8 + j
//   == row r (0..31), col kk*32 + q*8 + j of the [32 x 256] tile.
// Wave MFMA read at (kk, mt): lane(q,m) reads 16B at kk*2048 + q*512 + mt*256 + m*16
//   -> 16-lane contiguous 256B segments, conflict-free.
// Weight traffic: 4 waves x 72KB = 288KB per block over 32 nodes (half of round-2's per-node cost).
__global__ __launch_bounds__(256, 3)
void level_kernel(const void* __restrict__ xbase, int level,
                  const int* __restrict__ idx,              // [NN,2] this level
                  const unsigned short* __restrict__ hprev, // [NN,DD] bf16
                  const float* __restrict__ cprev,          // [NN,DD] fp32 (out slab l-1)
                  unsigned short* __restrict__ hnew,        // [NN,DD] bf16
                  float* __restrict__ outh,                 // [NN,DD] fp32
                  float* __restrict__ outc,                 // [NN,DD] fp32 (c state for l+1)
                  const unsigned short* __restrict__ wpack,
                  const float* __restrict__ bias,
                  const unsigned short* __restrict__ hinit_b,
                  const float* __restrict__ cinit_f,
                  const int* __restrict__ flag,
                  int first) {
    __shared__ unsigned short xs[8192];   // 16 KB
    __shared__ unsigned short hs[8192];   // 16 KB
    __shared__ float cs[64 * 68];         // 17.4 KB, [s*32+r][68] padded rows

    const int tid = threadIdx.x;
    const int isf = *flag;
    const int bm  = blockIdx.x;
    const int yh  = blockIdx.y;           // d-half: 0 or 1

    // ---- stage x tile: 4 slots/thread (u octet-col, r row) ----
    {
        const int u0 = tid >> 4;          // 0..15
        const int r0 = tid & 15;
        #pragma unroll
        for (int du = 0; du < 2; ++du) {
            const int u = u0 + du * 16;   // 0..31 (octet of the 256-wide row)
            const int kk = u >> 2, q = u & 3;
            #pragma unroll
            for (int dr = 0; dr < 2; ++dr) {
                const int r = r0 + dr * 16;
                const size_t re = (size_t)level * NN * DIN + (size_t)(bm * BM + r) * DIN + u * 8;
                union { unsigned short us[8]; uint4 v; } t;
                if (isf) {
                    const float4* xr = (const float4*)((const float*)xbase + re);
                    float4 v0 = xr[0], v1 = xr[1];
                    t.us[0] = f2b(v0.x); t.us[1] = f2b(v0.y); t.us[2] = f2b(v0.z); t.us[3] = f2b(v0.w);
                    t.us[4] = f2b(v1.x); t.us[5] = f2b(v1.y); t.us[6] = f2b(v1.z); t.us[7] = f2b(v1.w);
                } else {
                    t.v = *(const uint4*)((const unsigned short*)xbase + re);
                }
                *(uint4*)&xs[kk * 1024 + q * 256 + r * 8] = t.v;
            }
        }
    }

    // ---- gather children h (full 128-d, bf16) and c (this d-half, fp32) ----
    // r varies fastest across lanes -> conflict-free LDS b128 writes.
    {
        const int r  = tid & 31;          // node row in tile
        const int sp = tid >> 5;          // 0..7
        const int s    = sp >> 2;         // child 0/1
        const int part = sp & 3;          // 32-ushort / 16-float chunk
        const int ai = idx[(bm * BM + r) * 2 + s];
        const int use_init = (first || ai < 0);

        const unsigned short* hsrc = use_init ? (hinit_b + part * 32)
                                              : (hprev + (size_t)ai * DD + part * 32);
        const int kk = s * 4 + part;      // concat col block
        #pragma unroll
        for (int q = 0; q < 4; ++q)
            *(uint4*)&hs[kk * 1024 + q * 256 + r * 8] = ((const uint4*)hsrc)[q];

        const float* csrc = use_init ? (cinit_f + yh * 64 + part * 16)
                                     : (cprev + (size_t)ai * DD + yh * 64 + part * 16);
        float* cdst = &cs[(s * 32 + r) * 68 + part * 16];
        #pragma unroll
        for (int q = 0; q < 4; ++q)
            ((float4*)cdst)[q] = ((const float4*)csrc)[q];
    }
    __syncthreads();

    // ---- MFMA: wave handles d-range [yh*64 + wave*16, +16), 2 m-tiles, 9 gates ----
    const int lane = tid & 63;
    const int wave = tid >> 6;            // 0..3
    const int m    = lane & 15;
    const int q    = lane >> 4;
    const int dt   = yh * 4 + wave;       // global 16-d slice index
    const int d    = yh * 64 + wave * 16 + m;

    const unsigned short* wb = wpack + (size_t)dt * 4096 + (size_t)lane * 8;
    // fragment (g, kk) at wb + g*32768 + kk*512 (ushort units)

    f32x4 acc[9][2];
    #pragma unroll
    for (int g = 0; g < 9; ++g) { acc[g][0] = (f32x4)0.0f; acc[g][1] = (f32x4)0.0f; }

    #pragma unroll
    for (int kk = 0; kk < 8; ++kk) {
        const int xo = kk * 1024 + q * 256 + m * 8;
        bf16x8 a0 = *(const bf16x8*)&xs[xo];
        bf16x8 a1 = *(const bf16x8*)&xs[xo + 128];   // rows 16..31
        bf16x8 h0 = *(const bf16x8*)&hs[xo];
        bf16x8 h1 = *(const bf16x8*)&hs[xo + 128];
        #pragma unroll
        for (int g = 0; g < 4; ++g) {
            bf16x8 b = *(const bf16x8*)(wb + (size_t)g * 32768 + kk * 512);
            acc[g][0] = __builtin_amdgcn_mfma_f32_16x16x32_bf16(a0, b, acc[g][0], 0, 0, 0);
            acc[g][1] = __builtin_amdgcn_mfma_f32_16x16x32_bf16(a1, b, acc[g][1], 0, 0, 0);
        }
        #pragma unroll
        for (int g = 4; g < 9; ++g) {
            bf16x8 b = *(const bf16x8*)(wb + (size_t)g * 32768 + kk * 512);
            acc[g][0] = __builtin_amdgcn_mfma_f32_16x16x32_bf16(h0, b, acc[g][0], 0, 0, 0);
            acc[g][1] = __builtin_amdgcn_mfma_f32_16x16x32_bf16(h1, b, acc[g][1], 0, 0, 0);
        }
    }

    // ---- pointwise LSTM: acc[g][mt][j] -> node mt*16+q*4+j, dim d; c from LDS ----
    const float bfv = bias[d], biv = bias[128 + d], buv = bias[256 + d], bov = bias[384 + d];
    const int dloc = wave * 16 + m;
    #pragma unroll
    for (int mt = 0; mt < 2; ++mt) {
        #pragma unroll
        for (int j = 0; j < 4; ++j) {
            const int rr = mt * 16 + q * 4 + j;
            const int nd = bm * BM + rr;
            const float ca = cs[rr * 68 + dloc];
            const float cb = cs[(32 + rr) * 68 + dloc];
            const float fx = acc[0][mt][j] + bfv;
            const float ix = acc[1][mt][j] + biv;
            const float ux = acc[2][mt][j] + buv;
            const float ox = acc[3][mt][j] + bov;
            const float f1 = sig_(fx + acc[4][mt][j]);
            const float f2 = sig_(fx + acc[5][mt][j]);
            const float ig = sig_(ix + acc[6][mt][j]);
            const float ug = tanhf(ux + acc[7][mt][j]);
            const float og = sig_(ox + acc[8][mt][j]);
            const float nc = ig * ug + f1 * ca + f2 * cb;
            const float nh = og * tanhf(nc);
            const size_t o = (size_t)nd * DD + d;
            hnew[o] = f2b(nh);
            outh[o] = nh;
            outc[o] = nc;
        }
    }
}

extern "C" void kernel_launch(void* const* d_in, const int* in_sizes, int n_in,
                              void* d_out, int out_size, void* d_ws, size_t ws_size,
                              hipStream_t stream) {
    const void* tensor  = d_in[0];
    const int*  indices = (const int*)d_in[1];
    const void* h_init  = d_in[2];
    const void* c_init  = d_in[3];
    const void* Ww      = d_in[4];
    const void* Wb      = d_in[5];
    const void* Uf1     = d_in[6];
    const void* Uf2     = d_in[7];
    const void* Uiuo    = d_in[8];
    float* out = (float*)d_out;   // fp32: [h(L,N,D) | c(L,N,D)]

    char* wsb = (char*)d_ws;
    int* flag                = (int*)wsb;                               // @0
    unsigned short* wpack    = (unsigned short*)(wsb + 256);            // 589,824 B
    float* bias              = (float*)(wsb + 590336);                  // 2 KB
    unsigned short* hinit_b  = (unsigned short*)(wsb + 592640);         // 256 B
    float* cinit_f           = (float*)(wsb + 593152);                  // 512 B
    unsigned short* hb0      = (unsigned short*)(wsb + (1u << 20));             // 2 MB
    unsigned short* hb1      = (unsigned short*)(wsb + (1u << 20) + 2097152);   // 2 MB

    detect_kernel<<<1, 64, 0, stream>>>((const unsigned short*)tensor, flag);
    convert_kernel<<<1155, 256, 0, stream>>>(Ww, Wb, Uf1, Uf2, Uiuo, h_init, c_init,
                                             wpack, bias, hinit_b, cinit_f, flag);

    unsigned short* hp = hb0;
    unsigned short* hn = hb1;
    for (int l = 0; l < LVL; ++l) {
        const float* cprev = (l == 0) ? (const float*)out
                                      : (const float*)(out + (size_t)(LVL + l - 1) * NN * DD);
        // grid: (bx, yh). Linear ids of the two d-halves of a node tile differ by 256
        // (== 0 mod 8 XCDs) -> same XCD -> x tile read twice but L2-shared.
        level_kernel<<<dim3(NN / BM, 2), 256, 0, stream>>>(
            tensor, l,
            indices + (size_t)l * NN * 2,
            hp, cprev, hn,
            out + (size_t)l * NN * DD,
            out + (size_t)(LVL + l) * NN * DD,
            wpack, bias, hinit_b, cinit_f, flag, (l == 0) ? 1 : 0);
        unsigned short* th = hp; hp = hn; hn = th;
    }
}